// Round 10
// baseline (269.859 us; speedup 1.0000x reference)
//
#include <hip/hip_runtime.h>
#include <float.h>

#define T_TOTAL 32768
#define KC      8192
#define DIM     256

#define LOSS_IDX  ((size_t)T_TOTAL * DIM)      // 8388608
#define USAGE_IDX (LOSS_IDX + 1)

typedef short s16x8 __attribute__((ext_vector_type(8)));
typedef float f32x4 __attribute__((ext_vector_type(4)));

// ws layout (bytes):
#define WS_W2    0                 // f32[8192]
#define WS_FLAGS 32768             // i32[8192]
#define WS_GCNT  65536             // i32[64] token-group arrival counters
#define WS_CBF   65792             // u16[8192*256] = 4 MB

__device__ __forceinline__ unsigned short f2bf(float f) {
    unsigned int u = __float_as_uint(f);
    u += 0x7FFFu + ((u >> 16) & 1u);   // RTNE
    return (unsigned short)(u >> 16);
}

// ---------------------------------------------------------------------------
// prep: cb->bf16 + exact fp32 w2; flags zero (blocks 0..31); group counters
// zero (block 0); argmin keys (in out's z_q slots, 8 B/token) init ~0
// (blocks 0..127); scalars (block 0)
__global__ __launch_bounds__(256) void vq_prep(const float* __restrict__ cb,
                                               unsigned short* __restrict__ cbb,
                                               float* __restrict__ w2,
                                               int* __restrict__ flags,
                                               int* __restrict__ gcnt,
                                               float* __restrict__ out) {
    const int blk = blockIdx.x, tid = threadIdx.x;
    size_t i = (size_t)blk * 2048 + (size_t)tid * 8;
    float4 a = *(const float4*)(cb + i);
    float4 b = *(const float4*)(cb + i + 4);
    uint4 o;
    o.x = (unsigned)f2bf(a.x) | ((unsigned)f2bf(a.y) << 16);
    o.y = (unsigned)f2bf(a.z) | ((unsigned)f2bf(a.w) << 16);
    o.z = (unsigned)f2bf(b.x) | ((unsigned)f2bf(b.y) << 16);
    o.w = (unsigned)f2bf(b.z) | ((unsigned)f2bf(b.w) << 16);
    *(uint4*)(cbb + i) = o;
    float s = a.x * a.x + a.y * a.y + a.z * a.z + a.w * a.w
            + b.x * b.x + b.y * b.y + b.z * b.z + b.w * b.w;
    #pragma unroll
    for (int m = 1; m <= 16; m <<= 1) s += __shfl_xor(s, m);
    if ((tid & 31) == 0) w2[blk * 8 + (tid >> 5)] = s;
    if (blk < 32) flags[blk * 256 + tid] = 0;
    if (blk == 0 && tid < 64) gcnt[tid] = 0;
    if (blk < 128) {
        int t = blk * 256 + tid;   // 32768 tokens: key slot at out[t*256..+1]
        *(unsigned long long*)(out + ((size_t)t << 8)) = ~0ULL;
    }
    if (blk == 0 && tid == 0) { out[LOSS_IDX] = 0.0f; out[USAGE_IDX] = 0.0f; }
}

// ---------------------------------------------------------------------------
// main: block = 512 tokens x ONE QUARTER of the codebook (2048 codes).
// grid 256 = 64 token-groups x 4 quarters (quarter per XCD, L2-resident).
// 8 waves; wave w owns tokens [t0+w*64, +64), A in 128 regs.
//
// Main loop = R6 VERBATIM (best measured: 156us; probed from 5 directions —
// R2/R4 shared+barriers, R5 stagger, R7 reg-gather, R8 role-split all lost;
// 2 waves/SIMD is a register wall: af=128 VGPR/wave, and halving tokens/wave
// doubles ds_read-per-MFMA since fragments don't shrink with token count).
// All 8 waves issue IDENTICAL staging addresses in natural lockstep
// (no barriers, private 4-deep buffers) -> L1 dedups the L2 traffic.
// Per-wave pipeline:
//   iter n: lgkm(0) [prior ds_reads retired -> buf[n&3] recyclable]
//           STAGE(n+4 -> buf[n&3]); vmcnt(8) [drains st(n+1)]
//           ds_read frags(n+1) -> regB[(n+1)&1]; 16 MFMAs on regB[n&1]
//
// R9 NEW: fused gather. After the atomicMin merge, the 4 quarter-blocks of
// each token group rendezvous on gcnt[tb] (grid 256 = 1 block/CU forced by
// 136 KB LDS; capacity == grid -> ALL blocks co-resident -> spin is
// deadlock-free); then block (tb,cq) gathers tokens [t0+cq*128, +128).
// Keys are read with atomicMin(p, ~0ULL) (coherent RMW read; min with MAX
// is identity). A token's key is written ONLY by its group's 4 blocks, all
// fenced before incrementing gcnt -> keys final when count==4.
__global__ __launch_bounds__(512, 2) void vq_main(const unsigned short* __restrict__ cbb,
                                                  const float* __restrict__ w2g,
                                                  const float* __restrict__ z_e,
                                                  const float* __restrict__ cb,
                                                  float* __restrict__ out,
                                                  int* __restrict__ flags,
                                                  int* __restrict__ gcnt) {
    __shared__ unsigned short ca[8][4][2048];   // [wave][buf][4 KB] = 128 KB
    __shared__ float w2s[2048];                 // this quarter's w2, 8 KB
    __shared__ float wls[8];

    const int tid  = threadIdx.x;
    const int lane = tid & 63;
    const int w    = tid >> 6;        // 0..7 = token octile
    const int quad = lane >> 4;
    const int l15  = lane & 15;
    const int tb   = blockIdx.x >> 2; // token group (512 tokens)
    const int cq   = blockIdx.x & 3;  // code quarter
    const int t0   = tb * 512;
    const int cbase = cq * 2048;

    // staging: chunk c (0..63) = codes cbase + c*32 + row (row 0..31), as 4
    // k-windows kw (k in [kw*64,+64)) of 32 rows x 8 slots x 8 bf16, slot
    // XOR-swizzled by row for conflict-free ds_read_b128. 4 loads x 1 KB per
    // window. ALL 8 waves load the SAME addresses (w-independent) -> L1 dedup.
    const int srow = lane >> 3;       // 0..7
    const int ssl  = lane & 7;        // LDS slot position
    // addr(chunk C, kw KW, octet q) = pstage + C*8192 + q*2048 + KW*64
    //   == (cbase + C*32 + q*8 + srow)*DIM + KW*64 + (ssl^srow)*8
    const unsigned short* pstage = cbb + (size_t)(cbase + srow) * DIM + (ssl ^ srow) * 8;

    #define STAGE(PC, KW, BP)                                                           \
        {                                                                               \
            _Pragma("unroll")                                                           \
            for (int q = 0; q < 4; ++q) {                                               \
                __builtin_amdgcn_global_load_lds(                                       \
                    (const __attribute__((address_space(1))) void*)((PC) + (KW) * 64 + q * 2048), \
                    (__attribute__((address_space(3))) void*)(&ca[w][BP][q * 512]),     \
                    16, 0, 0);                                                          \
            }                                                                           \
        }

    // 4 hoisted per-lane LDS fragment pointers (kk,j); buffer select BP is a
    // compile-time +BP*2048 elements -> folds into ds_read offset immediate.
    const unsigned short* fragp[4];
    #pragma unroll
    for (int kk = 0; kk < 2; ++kk)
        #pragma unroll
        for (int j = 0; j < 2; ++j) {
            int row = j * 16 + l15;
            int sl = (kk * 4 + quad) ^ (l15 & 7);
            fragp[kk * 2 + j] = &ca[w][0][row * 64 + sl * 8];
        }

    #define READFRAGS(FB, BP)                                                           \
        {                                                                               \
            _Pragma("unroll")                                                           \
            for (int f = 0; f < 4; ++f)                                                 \
                (FB)[f] = *(const s16x8*)(fragp[f] + (BP) * 2048);                      \
        }

    // prologue: quarter w2 -> LDS; stage chunk 0's 4 windows; build A
    ((float4*)w2s)[tid] = ((const float4*)(w2g + cbase))[tid];
    STAGE(pstage, 0, 0); STAGE(pstage, 1, 1); STAGE(pstage, 2, 2); STAGE(pstage, 3, 3);
    s16x8 af[4][8];
    #pragma unroll
    for (int i = 0; i < 4; ++i) {
        #pragma unroll
        for (int ks = 0; ks < 8; ++ks) {
            const float* p = z_e + (size_t)(t0 + w * 64 + i * 16 + l15) * DIM + ks * 32 + quad * 8;
            float4 a = *(const float4*)p;
            float4 b = *(const float4*)(p + 4);
            s16x8 v;
            v[0] = (short)f2bf(a.x); v[1] = (short)f2bf(a.y);
            v[2] = (short)f2bf(a.z); v[3] = (short)f2bf(a.w);
            v[4] = (short)f2bf(b.x); v[5] = (short)f2bf(b.y);
            v[6] = (short)f2bf(b.z); v[7] = (short)f2bf(b.w);
            af[i][ks] = v;
        }
    }

    float best[4][4];
    int   bidx[4][4];
    #pragma unroll
    for (int i = 0; i < 4; ++i)
        #pragma unroll
        for (int r = 0; r < 4; ++r) { best[i][r] = FLT_MAX; bidx[i][r] = 0x7FFFFFFF; }

    // prime: drain ALL prologue VMEM, publish w2s; read window 0.
    // (no barriers in the loop: ca is wave-private)
    s16x8 regB[2][4];
    __builtin_amdgcn_s_waitcnt(0x0F70);   // vmcnt(0)
    __syncthreads();                       // w2s published
    READFRAGS(regB[0], 0);

    for (int c = 0; c < 64; ++c) {
        f32x4 acc[4][2];
        #pragma unroll
        for (int i = 0; i < 4; ++i)
            #pragma unroll
            for (int j = 0; j < 2; ++j) acc[i][j] = (f32x4){0.f, 0.f, 0.f, 0.f};

        // next-chunk staging base (dummy wrap at c=63 keeps accounting uniform)
        const unsigned short* pcn = pstage + ((size_t)((c + 1) & 63) << 13);

        #pragma unroll
        for (int kw = 0; kw < 4; ++kw) {
            // n = c*4 + kw; n&3 == kw
            // prior ds_reads retired -> buf[kw] is recyclable for staging
            __builtin_amdgcn_s_waitcnt(0xC07F);   // lgkmcnt(0), vmcnt/exp unconstrained
            STAGE(pcn, kw, kw);                   // window n+4 -> buf[n&3]
            // drain staging of window n+1 (leaves newest 8 = st(n+3), st(n+4))
            __builtin_amdgcn_s_waitcnt(0x0F78);   // vmcnt(8), lgkm/exp unconstrained
            READFRAGS(regB[(kw + 1) & 1], (kw + 1) & 3);
            // 16 MFMAs on window n (fragments read one phase ago)
            const s16x8* cur = regB[kw & 1];
            __builtin_amdgcn_s_setprio(1);
            #pragma unroll
            for (int kk = 0; kk < 2; ++kk)
                #pragma unroll
                for (int i = 0; i < 4; ++i)
                    #pragma unroll
                    for (int j = 0; j < 2; ++j)
                        acc[i][j] = __builtin_amdgcn_mfma_f32_16x16x32_bf16(af[i][kw * 2 + kk], cur[kk * 2 + j], acc[i][j], 0, 0, 0);
            __builtin_amdgcn_s_setprio(0);
        }

        // fold chunk c into running argmin: score = w2[col] - 2*dot
        #pragma unroll
        for (int j = 0; j < 2; ++j) {
            int col = cbase + c * 32 + j * 16 + l15;
            float w2v = w2s[c * 32 + j * 16 + l15];
            #pragma unroll
            for (int i = 0; i < 4; ++i)
                #pragma unroll
                for (int r = 0; r < 4; ++r) {
                    float s = fmaf(-2.0f, acc[i][j][r], w2v);
                    if (s < best[i][r]) { best[i][r] = s; bidx[i][r] = col; }  // ascending col: < keeps lowest
                }
        }
    }

    // cross-lane argmin over the 16 cols held per token row, then global
    // atomicMin merge across the 4 code-quarter blocks (monotonic u64 key)
    #pragma unroll
    for (int i = 0; i < 4; ++i)
        #pragma unroll
        for (int r = 0; r < 4; ++r) {
            float b = best[i][r]; int ix = bidx[i][r];
            #pragma unroll
            for (int m = 1; m < 16; m <<= 1) {
                float ob = __shfl_xor(b, m);
                int   oi = __shfl_xor(ix, m);
                if (ob < b || (ob == b && oi < ix)) { b = ob; ix = oi; }
            }
            if (l15 == 0) {
                unsigned int fb = __float_as_uint(b);
                fb = (fb & 0x80000000u) ? ~fb : (fb | 0x80000000u);   // monotonic key
                unsigned long long key = ((unsigned long long)fb << 32) | (unsigned int)ix;
                int tok = t0 + w * 64 + i * 16 + quad * 4 + r;
                atomicMin((unsigned long long*)(out + ((size_t)tok << 8)), key);
            }
        }

    // ---- group rendezvous: the 4 quarter-blocks of token group tb ----
    __threadfence();                       // atomicMins device-visible (drains vm)
    __syncthreads();                       // all 8 waves' mins fenced
    if (tid == 0) {
        atomicAdd(&gcnt[tb], 1);
        while (atomicAdd(&gcnt[tb], 0) < 4) __builtin_amdgcn_s_sleep(2);
    }
    __syncthreads();

    // ---- fused gather: this block -> tokens [t0 + cq*128, +128) ----
    // wave w owns 16 tokens; lanes 0..15 fetch the 16 final keys in parallel
    // via identity-RMW (coherent across XCDs), broadcast via shfl.
    const int gbase = t0 + cq * 128 + w * 16;
    unsigned long long mykey = 0;
    if (lane < 16)
        mykey = atomicMin((unsigned long long*)(out + ((size_t)(gbase + lane) << 8)), ~0ULL);
    int myk = (int)(unsigned int)(mykey & 0xFFFFFFFFull);

    float lsum = 0.0f;
    #pragma unroll 4
    for (int i = 0; i < 16; ++i) {
        int tok = gbase + i;
        int k = __shfl(myk, i);
        if (lane == 0) flags[k] = 1;   // benign race; usage kernel reads later
        float4 cv = *(const float4*)(cb + (size_t)k * DIM + lane * 4);
        float4 zv = *(const float4*)(z_e + (size_t)tok * DIM + lane * 4);
        float dx = zv.x - cv.x, dy = zv.y - cv.y, dz = zv.z - cv.z, dw = zv.w - cv.w;
        lsum += dx * dx + dy * dy + dz * dz + dw * dw;
        *(float4*)(out + ((size_t)tok << 8) + lane * 4) = cv;
    }
    #pragma unroll
    for (int m = 32; m >= 1; m >>= 1) lsum += __shfl_xor(lsum, m);
    if (lane == 0) wls[w] = lsum;
    __syncthreads();
    if (tid == 0) {
        float bsum = 0.0f;
        #pragma unroll
        for (int q = 0; q < 8; ++q) bsum += wls[q];
        // loss = codebook + 0.25*commitment = 1.25 * mean(diff^2)
        atomicAdd(out + LOSS_IDX, bsum * (1.25f / (float)LOSS_IDX));
    }
}

// ---------------------------------------------------------------------------
__global__ __launch_bounds__(256) void vq_usage(const int* __restrict__ flags,
                                                float* __restrict__ out) {
    __shared__ int ws[4];
    int tid = threadIdx.x;
    int s = 0;
    for (int i = tid; i < KC; i += 256) s += flags[i];
    #pragma unroll
    for (int m = 32; m >= 1; m >>= 1) s += __shfl_xor(s, m);
    if ((tid & 63) == 0) ws[tid >> 6] = s;
    __syncthreads();
    if (tid == 0) out[USAGE_IDX] = (float)(ws[0] + ws[1] + ws[2] + ws[3]) / (float)KC;
}

// ---------------------------------------------------------------------------
extern "C" void kernel_launch(void* const* d_in, const int* in_sizes, int n_in,
                              void* d_out, int out_size, void* d_ws, size_t ws_size,
                              hipStream_t stream) {
    (void)in_sizes; (void)n_in; (void)out_size; (void)ws_size;
    const float* z_e = (const float*)d_in[0];
    const float* cb  = (const float*)d_in[1];
    float* out = (float*)d_out;

    char* ws = (char*)d_ws;
    float* w2    = (float*)(ws + WS_W2);
    int*   flags = (int*)(ws + WS_FLAGS);
    int*   gcnt  = (int*)(ws + WS_GCNT);
    unsigned short* cbb = (unsigned short*)(ws + WS_CBF);

    vq_prep<<<KC / 8, 256, 0, stream>>>(cb, cbb, w2, flags, gcnt, out);
    vq_main<<<256, 512, 0, stream>>>(cbb, w2, z_e, cb, out, flags, gcnt);
    vq_usage<<<1, 256, 0, stream>>>(flags, out);
}